// Round 1
// baseline (15054.689 us; speedup 1.0000x reference)
//
#include <hip/hip_runtime.h>

namespace {

constexpr int Vv = 30000, Ll = 400, Bb = 16, Tt = 145;
constexpr int Ee = 100, EHh = 150, DHh = 200, ENc = 300;
constexpr int SOS_TOK = 1;
constexpr int G3E = 450;   // 3*EH
// d_out used as scratch before decoder writes it (time-disjoint):
constexpr long SO_EMB = 0;                                  // [400][16][100]
constexpr long SO_GIF = SO_EMB + (long)Ll*Bb*Ee;            // [400][16][450]
constexpr long SO_GIB = SO_GIF + (long)Ll*Bb*G3E;
constexpr long SO_ENC = SO_GIB + (long)Ll*Bb*G3E;           // [400][16][300]

// ws float offsets
constexpr long OFF_M    = 0;                                // [400][16][200]
constexpr long OFF_N    = OFF_M + (long)Ll*Bb*DHh;          // [400][16][100]
constexpr long OFF_Q    = OFF_N + (long)Ll*Bb*Ee;           // [400][16]
constexpr long OFF_PART = OFF_Q + (long)Ll*Bb;              // [200][16][102]
constexpr long OFF_PREH = OFF_PART + 200L*Bb*102;           // [16][104]
constexpr long OFF_PRE  = OFF_PREH + (long)Bb*104;          // [16][100]
constexpr long OFF_HDEC = OFF_PRE + (long)Bb*100;           // [2][16][200]
constexpr long OFF_HENC = OFF_HDEC + 2L*Bb*DHh;             // [2dir][2par][16][150]
constexpr long OFF_COVER= OFF_HENC + 4L*Bb*EHh;             // [16][400]
constexpr long OFF_EXPE = OFF_COVER + (long)Bb*Ll;          // [2][400][16]
constexpr long OFF_PSUM = OFF_EXPE + 2L*Ll*Bb;              // [256][16]
constexpr long OFF_PPTR = OFF_PSUM + 256L*Bb;               // [2][16]
constexpr long OFF_ZATT = OFF_PPTR + 32;                    // [2][16]
constexpr long OFF_ZLOG = OFF_ZATT + 32;                    // [2][16]
constexpr long OFF_CAND = OFF_ZLOG + 32;                    // [2][16][400][2]
constexpr long WS_F32_END = OFF_CAND + 2L*Bb*Ll*2;
constexpr long PMAX_BYTE = WS_F32_END*4;                    // 8B aligned
constexpr long IWS_BYTE  = PMAX_BYTE + 256L*Bb*8;
// iws int offsets
constexpr int ISVL=0, IGV=6400, IGLS=12800, ICG0=19216, INGR=23328;

struct Args {
  const int* itok;
  const float* emb;
  const float* Wfih; const float* Wfhh; const float* bfih; const float* bfhh;
  const float* Wbih; const float* Wbhh; const float* bbih; const float* bbhh;
  const float* adW; const float* adb;
  const float* dWih; const float* dWhh; const float* dbih; const float* dbhh;
  const float* bilW; const float* bilb; const float* cw;
  const float* ptrW; const float* ptrb;
  const float* preW; const float* preb; const float* outb;
  float* out; float* ws; unsigned long long* pmax; int* iws;
};

__device__ __forceinline__ int chunkStart(int c){ return c*117 + (c<48? c:48); }
__device__ __forceinline__ int chunkSize(int c){ return 117 + (c<48?1:0); }
__device__ __forceinline__ float sigm(float x){ return 1.f/(1.f+expf(-x)); }
__device__ __forceinline__ unsigned long long packvi(float val, int v){
  return ((unsigned long long)__float_as_uint(val)<<32) | (unsigned)(~(unsigned)v);
}
// deterministic 256-thread block reduce (uniform control flow only)
__device__ __forceinline__ float blockReduce256(float v, float* tmp, int tid){
  for (int off=32; off; off>>=1) v += __shfl_down(v, off);
  __syncthreads();
  if ((tid&63)==0) tmp[tid>>6] = v;
  __syncthreads();
  return tmp[0]+tmp[1]+tmp[2]+tmp[3];
}

// ---------------- init: embedding gather + zero state ----------------
__global__ void kInit0(Args a){
  int g = blockIdx.x*blockDim.x + threadIdx.x;
  int NT = gridDim.x*blockDim.x;
  for (long idx=g; idx<(long)Ll*Bb*Ee; idx+=NT){
    int l = idx/(Bb*Ee); int r = idx%(Bb*Ee); int b=r/Ee; int e=r%Ee;
    int tk = a.itok[l*Bb+b];
    a.out[SO_EMB+idx] = a.emb[(long)tk*Ee+e];
  }
  for (int idx=g; idx<Bb*Ll; idx+=NT) a.ws[OFF_COVER+idx]=0.f;
  for (int idx=g; idx<4*Bb*EHh; idx+=NT) a.ws[OFF_HENC+idx]=0.f;
}

// ---------------- gi = emb @ Wih^T + bih (both dirs) ----------------
__global__ __launch_bounds__(1024) void kGi(Args a){
  long g = blockIdx.x*(long)blockDim.x + threadIdx.x;
  long NT = gridDim.x*(long)blockDim.x;
  for (long o=g; o<2L*Ll*Bb*G3E; o+=NT){
    int dir = (int)(o/((long)Ll*Bb*G3E));
    long rr = o%((long)Ll*Bb*G3E);
    long lb = rr/G3E; int gg = (int)(rr%G3E);
    const float* Wih = dir? a.Wbih : a.Wfih;
    const float* bih = dir? a.bbih : a.bfih;
    const float* x = a.out + SO_EMB + lb*Ee;
    const float* w = Wih + (long)gg*Ee;
    float acc = bih[gg];
    for (int k=0;k<Ee;k++) acc += x[k]*w[k];
    a.out[(dir? SO_GIB : SO_GIF) + lb*G3E + gg] = acc;
  }
}

// ---------------- encoder step s (fwd blocks 0..74, bwd 75..149) ----------------
__global__ void kEnc(Args a, int s){
  int bi=blockIdx.x, tid=threadIdx.x;
  int dir = bi/75; int jp = bi%75; int j0 = jp*2;
  int l = dir? (Ll-1-s) : s;
  const float* Whh = dir? a.Wbhh : a.Wfhh;
  const float* bhh = dir? a.bbhh : a.bfhh;
  const float* giB = a.out + (dir? SO_GIB : SO_GIF) + (long)(l*Bb)*G3E;
  int rp = (s&1)^1, wp = s&1;
  const float* hsrc = a.ws + OFF_HENC + (long)(dir*2+rp)*Bb*EHh;
  float*       hdst = a.ws + OFF_HENC + (long)(dir*2+wp)*Bb*EHh;
  __shared__ float hp[Bb*EHh];
  __shared__ float gh[6][Bb];
  for (int i=tid;i<Bb*EHh;i+=256) hp[i]=hsrc[i];
  __syncthreads();
  if (tid < 96){
    int r6 = tid/16, b = tid%16;
    int row = (r6/2)*EHh + j0 + (r6&1);
    const float* w = Whh + (long)row*EHh;
    const float* h = hp + b*EHh;
    float acc=0;
    for (int k=0;k<EHh;k++) acc += w[k]*h[k];
    gh[r6][b] = acc + bhh[row];
  }
  __syncthreads();
  if (tid < 32){
    int b = tid>>1, jl = tid&1, jj = j0+jl;
    float r = sigm(giB[b*G3E + jj]        + gh[0+jl][b]);
    float z = sigm(giB[b*G3E + EHh + jj]  + gh[2+jl][b]);
    float n = tanhf(giB[b*G3E + 2*EHh + jj] + r*gh[4+jl][b]);
    float hv = (1.f-z)*n + z*hp[b*EHh+jj];
    hdst[b*EHh+jj] = hv;
    a.out[SO_ENC + (long)(l*Bb+b)*ENc + dir*EHh + jj] = hv;
  }
}

// ---------------- M,N,Q precompute + h0 ----------------
__global__ __launch_bounds__(1024) void kI2(Args a){
  long g = blockIdx.x*(long)blockDim.x + threadIdx.x;
  long NT = gridDim.x*(long)blockDim.x;
  const float* enc = a.out + SO_ENC;
  for (long o=g;o<(long)Ll*Bb*DHh;o+=NT){
    long lb=o/DHh; int j=(int)(o%DHh);
    const float* er=enc+lb*ENc; const float* w=a.bilW+(long)j*ENc;
    float acc=0; for(int e=0;e<ENc;e++) acc+=er[e]*w[e];
    a.ws[OFF_M+o]=acc;
  }
  for (long o=g;o<(long)Ll*Bb*Ee;o+=NT){
    long lb=o/Ee; int k=(int)(o%Ee);
    const float* er=enc+lb*ENc; const float* w=a.preW+(long)k*500+DHh;
    float acc=0; for(int e=0;e<ENc;e++) acc+=er[e]*w[e];
    a.ws[OFF_N+o]=acc;
  }
  for (long o=g;o<(long)Ll*Bb;o+=NT){
    const float* er=enc+o*ENc; const float* w=a.ptrW+DHh;
    float acc=0; for(int e=0;e<ENc;e++) acc+=er[e]*w[e];
    a.ws[OFF_Q+o]=acc;
  }
  for (long o=g;o<(long)Bb*DHh;o+=NT){
    int b=(int)(o/DHh); int j=(int)(o%DHh);
    float acc=a.adb[j];
    const float* w=a.adW+(long)j*ENc;
    const float* hf=a.ws+OFF_HENC + (0*2+1)*(long)Bb*EHh + b*EHh;   // fwd, parity of s=399 is 1
    const float* hb=a.ws+OFF_HENC + (1*2+1)*(long)Bb*EHh + b*EHh;
    for(int e=0;e<EHh;e++) acc+=hf[e]*w[e];
    for(int e=0;e<EHh;e++) acc+=hb[e]*w[EHh+e];
    a.ws[OFF_HDEC + 1L*Bb*DHh + o]=acc;   // hdec parity-1 = h0
  }
}

// ---------------- sort scatter indices, build groups/chunk offsets ----------------
__global__ void kSort(Args a){
  int b=blockIdx.x, tid=threadIdx.x;
  __shared__ int key[512];
  __shared__ int gflag[512];
  __shared__ int gid[512];
  key[tid] = (tid<Ll)? (a.itok[tid*Bb+b]*Ll + tid) : 0x7FFFFFFF;
  __syncthreads();
  for (int k=2;k<=512;k<<=1){
    for (int j=k>>1;j>0;j>>=1){
      int ixj = tid^j;
      if (ixj>tid){
        int x=key[tid], y=key[ixj];
        bool up = ((tid&k)==0);
        if ((x>y)==up){ key[tid]=y; key[ixj]=x; }
      }
      __syncthreads();
    }
  }
  int* svl=a.iws+ISVL+b*Ll; int* gvv=a.iws+IGV+b*Ll;
  int* gls=a.iws+IGLS+b*401; int* cg0=a.iws+ICG0+b*257;
  if (tid<Ll) svl[tid]=key[tid]%Ll;
  gflag[tid] = (tid<Ll)? ((tid==0)||(key[tid]/Ll != key[tid-1]/Ll)) : 0;
  __syncthreads();
  gid[tid]=gflag[tid]; __syncthreads();
  for (int off=1;off<512;off<<=1){
    int v = gid[tid] + ((tid>=off)? gid[tid-off]:0);
    __syncthreads(); gid[tid]=v; __syncthreads();
  }
  if (tid<Ll && gflag[tid]){ int g=gid[tid]-1; gvv[g]=key[tid]/Ll; gls[g]=tid; }
  __syncthreads();
  int ng = gid[Ll-1];
  if (tid==0){ gls[ng]=Ll; a.iws[INGR+b]=ng; }
  __syncthreads();
  for (int c=tid;c<=256;c+=512){
    int target = (c<256)? chunkStart(c) : 0x7FFFFFFF;
    int lo=0, hi=ng;
    while(lo<hi){ int mid=(lo+hi)>>1; if (gvv[mid]<target) lo=mid+1; else hi=mid; }
    cg0[c]=lo;
  }
}

// ---------------- decoder K1: finalize argmax(t-1) -> tok, GRU gates -> h(t) ----------------
__global__ __launch_bounds__(1024) void kG(Args a, int t){
  int bi=blockIdx.x, tid=threadIdx.x;
  int q=t&1, p1=q^1;
  __shared__ int tokL[Bb];
  __shared__ float xL[Bb][Ee];
  __shared__ float hL[Bb][DHh];
  __shared__ float zred[Bb][17];
  __shared__ unsigned long long mred[Bb][17];
  if (t==0){
    if (tid<Bb) tokL[tid]=SOS_TOK;
  } else {
    if (tid<256){
      int b=tid>>4, seg=tid&15;
      float zs=0;
      for (int c=seg;c<256;c+=16) zs += a.ws[OFF_PSUM + c*Bb + b];
      zred[b][seg]=zs;
    }
    __syncthreads();
    if (tid<Bb){
      float z=0;
      for (int s2=0;s2<16;s2++) z+=zred[tid][s2];
      zred[tid][16]=z;
      a.ws[OFF_ZLOG + p1*Bb + tid]=z;   // identical across blocks (benign)
    }
    __syncthreads();
    if (tid<256){
      int b=tid>>4, seg=tid&15;
      float Z=zred[b][16];
      unsigned long long best=0;
      for (int c=seg;c<256;c+=16){
        unsigned long long pm=a.pmax[c*Bb+b];
        float ev=__uint_as_float((unsigned)(pm>>32));
        int v=(int)(~(unsigned)(pm & 0xFFFFFFFFull));
        unsigned long long pk=packvi(ev/Z, v);
        if (pk>best) best=pk;
      }
      int ng=a.iws[INGR+b];
      const float* cd=a.ws+OFF_CAND + ((long)p1*Bb + b)*Ll*2;
      const int* gvv=a.iws+IGV+b*Ll;
      for (int g=seg;g<ng;g+=16){
        float val = cd[g*2]/Z + cd[g*2+1];
        unsigned long long pk=packvi(val, gvv[g]);
        if (pk>best) best=pk;
      }
      mred[b][seg]=best;
    }
    __syncthreads();
    if (tid<Bb){
      unsigned long long best=0;
      for (int s2=0;s2<16;s2++) if (mred[tid][s2]>best) best=mred[tid][s2];
      tokL[tid]=(int)(~(unsigned)(best & 0xFFFFFFFFull));
    }
  }
  __syncthreads();
  for (int i=tid;i<Bb*Ee;i+=1024){ int b=i/Ee, e=i%Ee; xL[b][e]=a.emb[(long)tokL[b]*Ee+e]; }
  const float* hprev=a.ws+OFF_HDEC + (long)p1*Bb*DHh;
  for (int i=tid;i<Bb*DHh;i+=1024) hL[i/DHh][i%DHh]=hprev[i];
  __syncthreads();
  int j0=bi*3, nj=(j0+3<=DHh)?3:(DHh-j0);
  int pair=tid>>4, lane=tid&15;
  if (pair < Bb*nj){
    int b=pair/nj, j=j0+pair%nj;
    float air=0,aiz=0,ain=0,ahr=0,ahz=0,ahn=0;
    const float* x=xL[b];
    for (int k=lane;k<Ee;k+=16){
      float xv=x[k];
      air+=xv*a.dWih[(long)j*Ee+k];
      aiz+=xv*a.dWih[(long)(DHh+j)*Ee+k];
      ain+=xv*a.dWih[(long)(2*DHh+j)*Ee+k];
    }
    const float* h=hL[b];
    for (int k=lane;k<DHh;k+=16){
      float hv=h[k];
      ahr+=hv*a.dWhh[(long)j*DHh+k];
      ahz+=hv*a.dWhh[(long)(DHh+j)*DHh+k];
      ahn+=hv*a.dWhh[(long)(2*DHh+j)*DHh+k];
    }
    for (int off=8;off;off>>=1){
      air+=__shfl_xor(air,off,16); aiz+=__shfl_xor(aiz,off,16); ain+=__shfl_xor(ain,off,16);
      ahr+=__shfl_xor(ahr,off,16); ahz+=__shfl_xor(ahz,off,16); ahn+=__shfl_xor(ahn,off,16);
    }
    if (lane==0){
      float r=sigm(air + a.dbih[j] + ahr + a.dbhh[j]);
      float z=sigm(aiz + a.dbih[DHh+j] + ahz + a.dbhh[DHh+j]);
      float n=tanhf(ain + a.dbih[2*DHh+j] + r*(ahn + a.dbhh[2*DHh+j]));
      float hv=(1.f-z)*n + z*hL[b][j];
      a.ws[OFF_HDEC + (long)q*Bb*DHh + b*DHh + j]=hv;
    }
  }
}

// ---------------- decoder K2: cover update, energy exp, attention partials, pre_h ----------------
__global__ void kE(Args a, int t){
  int bi=blockIdx.x, tid=threadIdx.x;
  int q=t&1, p1=q^1;
  __shared__ float hL[Bb*DHh];
  const float* hdec=a.ws+OFF_HDEC + (long)q*Bb*DHh;
  for (int i=tid;i<Bb*DHh;i+=256) hL[i]=hdec[i];
  __syncthreads();
  if (bi<200){
    __shared__ float exL[2][Bb];
    int unit=tid>>3, lane=tid&7;
    if (unit<32){
      int lloc=unit>>4, b=unit&15;
      int l=bi*2+lloc;
      const float* Mr=a.ws+OFF_M + (long)(l*Bb+b)*DHh;
      const float* h=hL+b*DHh;
      float acc=0;
      for (int k=lane;k<DHh;k+=8) acc+=h[k]*Mr[k];
      for (int off=4;off;off>>=1) acc+=__shfl_xor(acc,off,8);
      if (lane==0){
        float* cov=a.ws+OFF_COVER + b*Ll + l;
        if (t>0){
          float ap=a.ws[OFF_EXPE + (long)p1*Ll*Bb + l*Bb + b] / a.ws[OFF_ZATT + p1*Bb + b];
          *cov += ap;
        }
        float en = acc + a.bilb[0] + a.cw[0]*logf(*cov + 1e-31f);
        float ex = expf(en);
        a.ws[OFF_EXPE + (long)q*Ll*Bb + l*Bb + b]=ex;
        exL[lloc][b]=ex;
      }
    }
    __syncthreads();
    float* part=a.ws+OFF_PART + (long)bi*Bb*102;
    int l0=bi*2;
    for (int u=tid;u<Bb*102;u+=256){
      int b2=u/102, kk=u%102;
      float e0=exL[0][b2], e1=exL[1][b2];
      float s;
      if (kk<100)      s = e0*a.ws[OFF_N+(long)(l0*Bb+b2)*Ee+kk] + e1*a.ws[OFF_N+(long)((l0+1)*Bb+b2)*Ee+kk];
      else if (kk==100) s = e0*a.ws[OFF_Q+l0*Bb+b2] + e1*a.ws[OFF_Q+(l0+1)*Bb+b2];
      else              s = e0+e1;
      part[b2*102+kk]=s;
    }
  } else {
    int i=bi-200;         // 0..12
    int k0=i*8;
    int unit=tid>>1, lane=tid&1;
    if (unit<128){
      int b=unit>>3, kr=unit&7;
      int k=k0+kr;
      if (k<=Ee){         // k<100: pre rows; k==100: ptr row
        const float* w=(k<Ee)? (a.preW+(long)k*500) : a.ptrW;
        const float* h=hL+b*DHh;
        float acc=0;
        for (int j=lane;j<DHh;j+=2) acc+=h[j]*w[j];
        acc+=__shfl_xor(acc,1,2);
        if (lane==0) a.ws[OFF_PREH + b*104 + k]=acc;
      }
    }
  }
}

// ---------------- decoder K3: reduce partials -> pre, p_ptr, Z_att ----------------
__global__ void kP(Args a, int t){
  int blk=blockIdx.x, tid=threadIdx.x; int q=t&1;
  int b=blk>>4, kc=blk&15;
  const float* part=a.ws+OFF_PART;
  __shared__ float tmp[4];
  __shared__ float zLs;
  float zp=0;
  for (int lb=tid;lb<200;lb+=256) zp+=part[((long)lb*Bb+b)*102+101];
  float Z=blockReduce256(zp,tmp,tid);
  if (tid==0) zLs=Z;
  __syncthreads();
  Z=zLs;
  if (kc==15){
    float qp=0;
    for (int lb=tid;lb<200;lb+=256) qp+=part[((long)lb*Bb+b)*102+100];
    float qs=blockReduce256(qp,tmp,tid);
    if (tid==0){
      float pp=sigm(qs/Z + a.ws[OFF_PREH+b*104+100] + a.ptrb[0]);
      a.ws[OFF_PPTR + q*Bb + b]=pp;
      a.ws[OFF_ZATT + q*Bb + b]=Z;
    }
  } else {
    int k0=kc*7, nk=(kc<14)?7:2;
    for (int kr=0;kr<nk;kr++){
      int k=k0+kr;
      float sp=0;
      for (int lb=tid;lb<200;lb+=256) sp+=part[((long)lb*Bb+b)*102+k];
      float s=blockReduce256(sp,tmp,tid);
      if (tid==0) a.ws[OFF_PRE + b*100 + k] = s/Z + a.ws[OFF_PREH+b*104+k] + a.preb[k];
    }
  }
}

// ---------------- decoder K4: writeback(t-1), logits+exp(t), psum/pmax/cand ----------------
__global__ __launch_bounds__(1024) void kL(Args a, int t){
  int c=blockIdx.x, tid=threadIdx.x;
  int q=t&1, p1=q^1;
  int v0=chunkStart(c), nv=chunkSize(c);
  __shared__ float preL[Bb][Ee];
  __shared__ float exL[118*Bb];
  __shared__ float ppq[Bb], zaq[Bb], pp1[Bb], zl1[Bb];
  for (int i=tid;i<Bb*Ee;i+=1024) preL[i/Ee][i%Ee]=a.ws[OFF_PRE+i];
  if (tid<Bb){
    ppq[tid]=a.ws[OFF_PPTR+q*Bb+tid]; zaq[tid]=a.ws[OFF_ZATT+q*Bb+tid];
    if (t>0){ pp1[tid]=a.ws[OFF_PPTR+p1*Bb+tid]; zl1[tid]=a.ws[OFF_ZLOG+p1*Bb+tid]; }
  }
  __syncthreads();
  if (t>0){
    for (int b2=0;b2<Bb;b2++){
      float sc=(1.f-pp1[b2])/zl1[b2];
      float* row=a.out + ((long)(t-1)*Bb+b2)*Vv;
      for (int vl=tid;vl<nv;vl+=1024) row[v0+vl]*=sc;
    }
    __syncthreads();
    if (tid<Bb){
      int b=tid;
      const int* cg0=a.iws+ICG0+b*257; const int* gvv=a.iws+IGV+b*Ll;
      const float* cd=a.ws+OFF_CAND + ((long)p1*Bb+b)*Ll*2;
      for (int g=cg0[c];g<cg0[c+1];g++){
        atomicAdd(a.out + ((long)(t-1)*Bb+b)*Vv + gvv[g], cd[g*2+1]*(1.f-pp1[b]));
      }
    }
    __syncthreads();
  }
  // logits + exp (coalesced over v)
  for (int b2=0;b2<Bb;b2++){
    const float4* pr=(const float4*)(&preL[b2][0]);
    float* row=a.out + ((long)t*Bb+b2)*Vv;
    for (int vl=tid;vl<nv;vl+=1024){
      int v=v0+vl;
      const float4* er=(const float4*)(a.emb + (long)v*Ee);
      float acc=a.outb[v];
      #pragma unroll
      for (int e4=0;e4<25;e4++){
        float4 A=er[e4], Bv=pr[e4];
        acc += A.x*Bv.x + A.y*Bv.y + A.z*Bv.z + A.w*Bv.w;
      }
      float ex=expf(acc);
      exL[vl*Bb+b2]=ex;
      row[v]=ex;
    }
  }
  __syncthreads();
  // per-wave (one wave per b) deterministic psum / pmax
  int w=tid>>6, lane=tid&63;
  {
    float s=0; unsigned long long m=0;
    for (int vl=lane;vl<nv;vl+=64){
      float ex=exL[vl*Bb+w];
      s+=ex;
      unsigned long long pk=packvi(ex, v0+vl);
      if (pk>m) m=pk;
    }
    for (int off=32;off;off>>=1){
      s+=__shfl_down(s,off);
      unsigned long long om=__shfl_down(m,off);
      if (om>m) m=om;
    }
    if (lane==0){ a.ws[OFF_PSUM+c*Bb+w]=s; a.pmax[c*Bb+w]=m; }
  }
  // candidate entries for this chunk's scatter groups
  if (tid<Bb){
    int b=tid;
    const int* cg0=a.iws+ICG0+b*257; const int* gvv=a.iws+IGV+b*Ll;
    const int* gls=a.iws+IGLS+b*401; const int* svl=a.iws+ISVL+b*Ll;
    float* cd=a.ws+OFF_CAND + ((long)q*Bb+b)*Ll*2;
    float pfac=ppq[b]/(1.f-ppq[b]);
    for (int g=cg0[c];g<cg0[c+1];g++){
      int v=gvv[g];
      float exv=exL[(v-v0)*Bb+b];
      float gs=0;
      for (int i2=gls[g];i2<gls[g+1];i2++) gs += a.ws[OFF_EXPE + (long)q*Ll*Bb + svl[i2]*Bb + b];
      cd[g*2]=exv;
      cd[g*2+1]=pfac*gs/zaq[b];
    }
  }
}

// ---------------- final writeback of step T-1 ----------------
__global__ void kW(Args a){
  int c=blockIdx.x, tid=threadIdx.x;
  int q=(Tt-1)&1;
  int v0=chunkStart(c), nv=chunkSize(c);
  __shared__ float Zr[Bb], pp[Bb];
  if (tid<Bb){
    float z=0;
    for (int cc=0;cc<256;cc++) z+=a.ws[OFF_PSUM+cc*Bb+tid];
    Zr[tid]=z; pp[tid]=a.ws[OFF_PPTR+q*Bb+tid];
  }
  __syncthreads();
  for (int b2=0;b2<Bb;b2++){
    float sc=(1.f-pp[b2])/Zr[b2];
    float* row=a.out + ((long)(Tt-1)*Bb+b2)*Vv;
    for (int vl=tid;vl<nv;vl+=256) row[v0+vl]*=sc;
  }
  __syncthreads();
  if (tid<Bb){
    int b=tid;
    const int* cg0=a.iws+ICG0+b*257; const int* gvv=a.iws+IGV+b*Ll;
    const float* cd=a.ws+OFF_CAND + ((long)q*Bb+b)*Ll*2;
    for (int g=cg0[c];g<cg0[c+1];g++){
      atomicAdd(a.out + ((long)(Tt-1)*Bb+b)*Vv + gvv[g], cd[g*2+1]*(1.f-pp[b]));
    }
  }
}

} // namespace

extern "C" void kernel_launch(void* const* d_in, const int* in_sizes, int n_in,
                              void* d_out, int out_size, void* d_ws, size_t ws_size,
                              hipStream_t stream) {
  Args a;
  a.itok=(const int*)d_in[0];
  a.emb =(const float*)d_in[1];
  a.Wfih=(const float*)d_in[2]; a.Wfhh=(const float*)d_in[3];
  a.bfih=(const float*)d_in[4]; a.bfhh=(const float*)d_in[5];
  a.Wbih=(const float*)d_in[6]; a.Wbhh=(const float*)d_in[7];
  a.bbih=(const float*)d_in[8]; a.bbhh=(const float*)d_in[9];
  a.adW =(const float*)d_in[10]; a.adb=(const float*)d_in[11];
  a.dWih=(const float*)d_in[12]; a.dWhh=(const float*)d_in[13];
  a.dbih=(const float*)d_in[14]; a.dbhh=(const float*)d_in[15];
  a.bilW=(const float*)d_in[16]; a.bilb=(const float*)d_in[17];
  a.cw  =(const float*)d_in[18];
  a.ptrW=(const float*)d_in[19]; a.ptrb=(const float*)d_in[20];
  a.preW=(const float*)d_in[21]; a.preb=(const float*)d_in[22];
  a.outb=(const float*)d_in[23];
  a.out =(float*)d_out;
  a.ws  =(float*)d_ws;
  a.pmax=(unsigned long long*)((char*)d_ws + PMAX_BYTE);
  a.iws =(int*)((char*)d_ws + IWS_BYTE);
  // requires ws_size >= ~9.5 MB (IWS_BYTE + 23344*4)

  kInit0<<<dim3(256),dim3(256),0,stream>>>(a);
  kGi<<<dim3(256),dim3(1024),0,stream>>>(a);
  for (int s=0;s<Ll;s++) kEnc<<<dim3(150),dim3(256),0,stream>>>(a,s);
  kI2<<<dim3(256),dim3(1024),0,stream>>>(a);
  kSort<<<dim3(16),dim3(512),0,stream>>>(a);
  for (int t=0;t<Tt;t++){
    kG<<<dim3(67),dim3(1024),0,stream>>>(a,t);
    kE<<<dim3(213),dim3(256),0,stream>>>(a,t);
    kP<<<dim3(256),dim3(256),0,stream>>>(a,t);
    kL<<<dim3(256),dim3(1024),0,stream>>>(a,t);
  }
  kW<<<dim3(256),dim3(256),0,stream>>>(a);
}